// Round 1
// baseline (257.675 us; speedup 1.0000x reference)
//
#include <hip/hip_runtime.h>
#include <math.h>

// Problem constants (from reference): B=8, T=16, P=197, C=1024, R=8
#define BB 8
#define TT 16
#define PP 197
#define CC 1024
#define RR 8
#define NROWS (BB * TT * PP)   // 25216 rows of (b,t,p)
#define NSEQ  (BB * PP)        // 1576 LSTM sequences
#define LORA_SCALE 2.0f        // alpha/rank = 16/8

// ---------- helpers ----------
__device__ __forceinline__ float sigf(float x) {
    // clamp for safety; gates are small in practice
    x = fminf(fmaxf(x, -30.f), 30.f);
    return 1.0f / (1.0f + __expf(-x));
}
__device__ __forceinline__ float tanh_fast(float x) {
    x = fminf(fmaxf(x, -15.f), 15.f);
    float e = __expf(-2.0f * x);
    return (1.0f - e) / (1.0f + e);
}
__device__ __forceinline__ float dot4(const float4& a, const float4& b) {
    return a.x * b.x + a.y * b.y + a.z * b.z + a.w * b.w;
}

// ---------- Kernel 1: LoRA down  red[row][r] = mask(b,t) * sum_c hs[row][c]*dw[r][c]
// One wave per 2 rows. down_w register-resident: lane owns cols {k*256 + lane*4 + j}.
__global__ __launch_bounds__(256) void k_down(const float* __restrict__ hs,
                                              const float* __restrict__ dw,
                                              const float* __restrict__ fm,
                                              float* __restrict__ red) {
    const int lane = threadIdx.x & 63;
    const int wave = (blockIdx.x * blockDim.x + threadIdx.x) >> 6;

    // preload down_w fragments: 128 floats/lane, coalesced 1KB per instruction
    float4 w[RR][4];
#pragma unroll
    for (int r = 0; r < RR; ++r)
#pragma unroll
        for (int k = 0; k < 4; ++k)
            w[r][k] = *(const float4*)(dw + r * CC + k * 256 + lane * 4);

    const int row0 = wave * 2;

    // load both rows up front for MLP
    float4 xa[4], xb[4];
    const float* rpa = hs + (size_t)row0 * CC;
    const float* rpb = hs + (size_t)(row0 + 1) * CC;
#pragma unroll
    for (int k = 0; k < 4; ++k) xa[k] = *(const float4*)(rpa + k * 256 + lane * 4);
#pragma unroll
    for (int k = 0; k < 4; ++k) xb[k] = *(const float4*)(rpb + k * 256 + lane * 4);

    float acca[RR], accb[RR];
#pragma unroll
    for (int r = 0; r < RR; ++r) {
        float a = 0.f, b = 0.f;
#pragma unroll
        for (int k = 0; k < 4; ++k) {
            a += dot4(xa[k], w[r][k]);
            b += dot4(xb[k], w[r][k]);
        }
        acca[r] = a; accb[r] = b;
    }
    // butterfly reduce across the 64 lanes (both rows interleaved to hide latency)
#pragma unroll
    for (int d = 32; d >= 1; d >>= 1) {
#pragma unroll
        for (int r = 0; r < RR; ++r) {
            acca[r] += __shfl_xor(acca[r], d, 64);
            accb[r] += __shfl_xor(accb[r], d, 64);
        }
    }
    if (lane == 0) {
        const float ma = fm[row0 / PP];        // index b*T + t
        const float mb = fm[(row0 + 1) / PP];
        float4* opa = (float4*)(red + (size_t)row0 * RR);
        float4* opb = (float4*)(red + (size_t)(row0 + 1) * RR);
        opa[0] = make_float4(acca[0] * ma, acca[1] * ma, acca[2] * ma, acca[3] * ma);
        opa[1] = make_float4(acca[4] * ma, acca[5] * ma, acca[6] * ma, acca[7] * ma);
        opb[0] = make_float4(accb[0] * mb, accb[1] * mb, accb[2] * mb, accb[3] * mb);
        opb[1] = make_float4(accb[4] * mb, accb[5] * mb, accb[6] * mb, accb[7] * mb);
    }
}

// ---------- Kernel 2: rank-8 LSTM over T. 8 lanes per sequence; lane owns rank slot r
// and computes its 4 gates (rows r, 8+r, 16+r, 24+r of w_ih/w_hh). h,c stay in regs;
// cross-rank terms gathered with __shfl within the 8-lane group.
__global__ __launch_bounds__(256) void k_lstm(const float* __restrict__ red,
                                              const float* __restrict__ fm,
                                              const float* __restrict__ w_ih,
                                              const float* __restrict__ w_hh,
                                              const float* __restrict__ b_ih,
                                              const float* __restrict__ b_hh,
                                              float* __restrict__ hsm) {
    const int tid = blockIdx.x * blockDim.x + threadIdx.x;
    const int n = tid >> 3;            // sequence index = b*P + p
    const int r = tid & 7;             // rank slot
    const int lane = threadIdx.x & 63;
    const int grp = lane & 56;         // first lane of this 8-lane group
    const bool valid = (n < NSEQ);

    // per-lane weights (64 floats -> registers); same-address across groups -> L1 broadcast
    float wi_i[8], wi_f[8], wi_g[8], wi_o[8];
    float wh_i[8], wh_f[8], wh_g[8], wh_o[8];
#pragma unroll
    for (int j = 0; j < 8; ++j) {
        wi_i[j] = w_ih[(r) * 8 + j];
        wi_f[j] = w_ih[(8 + r) * 8 + j];
        wi_g[j] = w_ih[(16 + r) * 8 + j];
        wi_o[j] = w_ih[(24 + r) * 8 + j];
        wh_i[j] = w_hh[(r) * 8 + j];
        wh_f[j] = w_hh[(8 + r) * 8 + j];
        wh_g[j] = w_hh[(16 + r) * 8 + j];
        wh_o[j] = w_hh[(24 + r) * 8 + j];
    }
    const float bi = b_ih[r] + b_hh[r];
    const float bf = b_ih[8 + r] + b_hh[8 + r];
    const float bg = b_ih[16 + r] + b_hh[16 + r];
    const float bo = b_ih[24 + r] + b_hh[24 + r];

    int b = 0, p = 0;
    if (valid) { b = n / PP; p = n - b * PP; }
    const size_t base = ((size_t)b * TT * PP + p) * RR + r;   // (B,T,P,R) layout
    const size_t tstride = (size_t)PP * RR;                   // 1576

    float h = 0.f, c = 0.f;
    for (int t = 0; t < TT; ++t) {
        const float x = valid ? red[base + (size_t)t * tstride] : 0.f;
        float gi = bi, gf = bf, gg = bg, go = bo;
#pragma unroll
        for (int j = 0; j < 8; ++j) {
            const float xv = __shfl(x, grp + j, 64);
            const float hv = __shfl(h, grp + j, 64);
            gi += wi_i[j] * xv + wh_i[j] * hv;
            gf += wi_f[j] * xv + wh_f[j] * hv;
            gg += wi_g[j] * xv + wh_g[j] * hv;
            go += wi_o[j] * xv + wh_o[j] * hv;
        }
        c = sigf(gf) * c + sigf(gi) * tanh_fast(gg);
        h = sigf(go) * tanh_fast(c);
        if (valid) hsm[base + (size_t)t * tstride] = h * fm[b * TT + t];
    }
}

// ---------- Kernel 3: LoRA up  out[row][c] = SCALE * sum_r hsm[row][r]*up[c][r]
// One wave per 2 rows; up_w register-resident (lane owns cols {k*256 + lane*4 + j}).
__global__ __launch_bounds__(256) void k_up(const float* __restrict__ hsm,
                                            const float* __restrict__ up,
                                            float* __restrict__ out) {
    const int lane = threadIdx.x & 63;
    const int wave = (blockIdx.x * blockDim.x + threadIdx.x) >> 6;

    float4 u[4][4][2];   // [k][j][half] : up_w rows for col c = k*256 + lane*4 + j
#pragma unroll
    for (int k = 0; k < 4; ++k)
#pragma unroll
        for (int j = 0; j < 4; ++j) {
            const float* pp = up + (size_t)(k * 256 + lane * 4 + j) * RR;
            u[k][j][0] = *(const float4*)(pp);
            u[k][j][1] = *(const float4*)(pp + 4);
        }

    const int row0 = wave * 2;
#pragma unroll
    for (int rr = 0; rr < 2; ++rr) {
        const int row = row0 + rr;
        const float* hp = hsm + (size_t)row * RR;
        float4 h0 = *(const float4*)(hp);
        float4 h1 = *(const float4*)(hp + 4);
        h0.x *= LORA_SCALE; h0.y *= LORA_SCALE; h0.z *= LORA_SCALE; h0.w *= LORA_SCALE;
        h1.x *= LORA_SCALE; h1.y *= LORA_SCALE; h1.z *= LORA_SCALE; h1.w *= LORA_SCALE;
        float* op = out + (size_t)row * CC;
#pragma unroll
        for (int k = 0; k < 4; ++k) {
            float4 o;
            o.x = dot4(h0, u[k][0][0]) + dot4(h1, u[k][0][1]);
            o.y = dot4(h0, u[k][1][0]) + dot4(h1, u[k][1][1]);
            o.z = dot4(h0, u[k][2][0]) + dot4(h1, u[k][2][1]);
            o.w = dot4(h0, u[k][3][0]) + dot4(h1, u[k][3][1]);
            *(float4*)(op + k * 256 + lane * 4) = o;
        }
    }
}

extern "C" void kernel_launch(void* const* d_in, const int* in_sizes, int n_in,
                              void* d_out, int out_size, void* d_ws, size_t ws_size,
                              hipStream_t stream) {
    const float* hs  = (const float*)d_in[0];  // (B,T,P,C)
    // d_in[1] = num_frames (int scalar) — fixed to T, unused
    const float* fm  = (const float*)d_in[2];  // (B,T)
    const float* dw  = (const float*)d_in[3];  // (R,C)
    const float* wih = (const float*)d_in[4];  // (4R,R)
    const float* whh = (const float*)d_in[5];  // (4R,R)
    const float* bih = (const float*)d_in[6];  // (4R,)
    const float* bhh = (const float*)d_in[7];  // (4R,)
    const float* up  = (const float*)d_in[8];  // (C,R)
    float* out = (float*)d_out;

    // workspace: red (NROWS*8 fp32 = 807KB) | hsm (same). Fully overwritten each call.
    float* red = (float*)d_ws;
    float* hsm = red + (size_t)NROWS * RR;

    // K1: 2 rows per wave, 4 waves per block -> 8 rows/block; 25216/8 = 3152 blocks
    k_down<<<NROWS / 8, 256, 0, stream>>>(hs, dw, fm, red);
    // K2: 8 lanes per sequence; 1576*8 = 12608 threads -> 50 blocks
    k_lstm<<<(NSEQ * 8 + 255) / 256, 256, 0, stream>>>(red, fm, wih, whh, bih, bhh, hsm);
    // K3: 2 rows per wave
    k_up<<<NROWS / 8, 256, 0, stream>>>(hsm, up, out);
}

// Round 2
// 210.646 us; speedup vs baseline: 1.2233x; 1.2233x over previous
//
#include <hip/hip_runtime.h>
#include <math.h>

// Problem constants: B=8, T=16, P=197, C=1024, R=8
#define BB 8
#define TT 16
#define PP 197
#define CC 1024
#define RR 8
#define NROWS (BB * TT * PP)   // 25216 rows of (b,t,p)
#define NPAIRS (NROWS / 2)     // 12608
#define NSEQ  (BB * PP)        // 1576 LSTM sequences
#define LORA_SCALE 2.0f        // alpha/rank = 16/8

__device__ __forceinline__ float sigf(float x) {
    x = fminf(fmaxf(x, -30.f), 30.f);
    return 1.0f / (1.0f + __expf(-x));
}
__device__ __forceinline__ float tanh_fast(float x) {
    x = fminf(fmaxf(x, -15.f), 15.f);
    float e = __expf(-2.0f * x);
    return (1.0f - e) / (1.0f + e);
}
__device__ __forceinline__ float dot4(const float4& a, const float4& b) {
    return a.x * b.x + a.y * b.y + a.z * b.z + a.w * b.w;
}

// ---------- Kernel 1: LoRA down.  red[row][r] = mask(b,t) * sum_c hs[row][c]*dw[r][c]
// down_w register-resident (coalesced preload, lane owns cols k*256+lane*4+j).
// Wave grid-strides over row-PAIRS so the 32KB weight preload is amortized ~6x.
__global__ __launch_bounds__(256) void k_down(const float* __restrict__ hs,
                                              const float* __restrict__ dw,
                                              const float* __restrict__ fm,
                                              float* __restrict__ red) {
    const int lane = threadIdx.x & 63;
    const int wid  = (blockIdx.x * blockDim.x + threadIdx.x) >> 6;
    const int nw   = (gridDim.x * blockDim.x) >> 6;

    // preload down_w: 128 floats/lane, coalesced (lane-stride 16B)
    float4 w[RR][4];
#pragma unroll
    for (int r = 0; r < RR; ++r)
#pragma unroll
        for (int k = 0; k < 4; ++k)
            w[r][k] = *(const float4*)(dw + r * CC + k * 256 + lane * 4);

    for (int pr = wid; pr < NPAIRS; pr += nw) {
        const int row0 = pr * 2;
        float4 xa[4], xb[4];
        const float* rpa = hs + (size_t)row0 * CC;
        const float* rpb = rpa + CC;
#pragma unroll
        for (int k = 0; k < 4; ++k) xa[k] = *(const float4*)(rpa + k * 256 + lane * 4);
#pragma unroll
        for (int k = 0; k < 4; ++k) xb[k] = *(const float4*)(rpb + k * 256 + lane * 4);

        float acca[RR], accb[RR];
#pragma unroll
        for (int r = 0; r < RR; ++r) {
            float a = 0.f, b = 0.f;
#pragma unroll
            for (int k = 0; k < 4; ++k) {
                a += dot4(xa[k], w[r][k]);
                b += dot4(xb[k], w[r][k]);
            }
            acca[r] = a; accb[r] = b;
        }
#pragma unroll
        for (int d = 32; d >= 1; d >>= 1) {
#pragma unroll
            for (int r = 0; r < RR; ++r) {
                acca[r] += __shfl_xor(acca[r], d, 64);
                accb[r] += __shfl_xor(accb[r], d, 64);
            }
        }
        if (lane == 0) {
            const float ma = fm[row0 / PP];
            const float mb = fm[(row0 + 1) / PP];
            float4* opa = (float4*)(red + (size_t)row0 * RR);
            opa[0] = make_float4(acca[0] * ma, acca[1] * ma, acca[2] * ma, acca[3] * ma);
            opa[1] = make_float4(acca[4] * ma, acca[5] * ma, acca[6] * ma, acca[7] * ma);
            opa[2] = make_float4(accb[0] * mb, accb[1] * mb, accb[2] * mb, accb[3] * mb);
            opa[3] = make_float4(accb[4] * mb, accb[5] * mb, accb[6] * mb, accb[7] * mb);
        }
    }
}

// ---------- Kernel 2: rank-8 LSTM over T. 8 lanes per sequence; lane owns rank slot r.
// All 16 x_t loads hoisted ahead of the serial h/c dependency chain.
__global__ __launch_bounds__(64) void k_lstm(const float* __restrict__ red,
                                             const float* __restrict__ fm,
                                             const float* __restrict__ w_ih,
                                             const float* __restrict__ w_hh,
                                             const float* __restrict__ b_ih,
                                             const float* __restrict__ b_hh,
                                             float* __restrict__ hsm) {
    const int tid = blockIdx.x * blockDim.x + threadIdx.x;
    const int n = tid >> 3;            // sequence index = b*P + p
    const int r = tid & 7;             // rank slot
    const int lane = threadIdx.x & 63;
    const int grp = lane & 56;
    if (n >= NSEQ) return;             // grid is exact (197*64 = NSEQ*8); safety only

    float wi_i[8], wi_f[8], wi_g[8], wi_o[8];
    float wh_i[8], wh_f[8], wh_g[8], wh_o[8];
#pragma unroll
    for (int j = 0; j < 8; ++j) {
        wi_i[j] = w_ih[(r) * 8 + j];
        wi_f[j] = w_ih[(8 + r) * 8 + j];
        wi_g[j] = w_ih[(16 + r) * 8 + j];
        wi_o[j] = w_ih[(24 + r) * 8 + j];
        wh_i[j] = w_hh[(r) * 8 + j];
        wh_f[j] = w_hh[(8 + r) * 8 + j];
        wh_g[j] = w_hh[(16 + r) * 8 + j];
        wh_o[j] = w_hh[(24 + r) * 8 + j];
    }
    const float bi = b_ih[r] + b_hh[r];
    const float bf = b_ih[8 + r] + b_hh[8 + r];
    const float bg = b_ih[16 + r] + b_hh[16 + r];
    const float bo = b_ih[24 + r] + b_hh[24 + r];

    const int b = n / PP, p = n - (n / PP) * PP;
    const size_t base = ((size_t)b * TT * PP + p) * RR + r;
    const size_t tstride = (size_t)PP * RR;

    float xs[TT], msk[TT];
#pragma unroll
    for (int t = 0; t < TT; ++t) xs[t] = red[base + (size_t)t * tstride];
#pragma unroll
    for (int t = 0; t < TT; ++t) msk[t] = fm[b * TT + t];

    float h = 0.f, c = 0.f;
#pragma unroll
    for (int t = 0; t < TT; ++t) {
        float gi = bi, gf = bf, gg = bg, go = bo;
#pragma unroll
        for (int j = 0; j < 8; ++j) {
            const float xv = __shfl(xs[t], grp + j, 64);
            const float hv = __shfl(h, grp + j, 64);
            gi += wi_i[j] * xv + wh_i[j] * hv;
            gf += wi_f[j] * xv + wh_f[j] * hv;
            gg += wi_g[j] * xv + wh_g[j] * hv;
            go += wi_o[j] * xv + wh_o[j] * hv;
        }
        c = sigf(gf) * c + sigf(gi) * tanh_fast(gg);
        h = sigf(go) * tanh_fast(c);
        hsm[base + (size_t)t * tstride] = h * msk[t];
    }
}

// ---------- Kernel 3: LoRA up.  out[row][c] = SCALE * sum_r hsm[row][r]*up[c][r]
// Lane owns cols {g*64 + lane}: up-preload has lane-stride 32B (2x coalesced cost,
// ONE-TIME per wave), stores are perfectly coalesced dwords. Wave grid-strides rows.
__global__ __launch_bounds__(256) void k_up(const float* __restrict__ hsm,
                                            const float* __restrict__ up,
                                            float* __restrict__ out) {
    const int lane = threadIdx.x & 63;
    const int wid  = (blockIdx.x * blockDim.x + threadIdx.x) >> 6;
    const int nw   = (gridDim.x * blockDim.x) >> 6;

    float4 u0[16], u1[16];   // up rows for col = g*64 + lane
#pragma unroll
    for (int g = 0; g < 16; ++g) {
        const float* pp = up + (size_t)(g * 64 + lane) * RR;
        u0[g] = *(const float4*)(pp);
        u1[g] = *(const float4*)(pp + 4);
    }

    for (int row = wid; row < NROWS; row += nw) {
        const float* hp = hsm + (size_t)row * RR;
        float4 h0 = *(const float4*)(hp);       // broadcast: all lanes same line
        float4 h1 = *(const float4*)(hp + 4);
        h0.x *= LORA_SCALE; h0.y *= LORA_SCALE; h0.z *= LORA_SCALE; h0.w *= LORA_SCALE;
        h1.x *= LORA_SCALE; h1.y *= LORA_SCALE; h1.z *= LORA_SCALE; h1.w *= LORA_SCALE;
        float* op = out + (size_t)row * CC + lane;
#pragma unroll
        for (int g = 0; g < 16; ++g) {
            op[g * 64] = dot4(h0, u0[g]) + dot4(h1, u1[g]);
        }
    }
}

extern "C" void kernel_launch(void* const* d_in, const int* in_sizes, int n_in,
                              void* d_out, int out_size, void* d_ws, size_t ws_size,
                              hipStream_t stream) {
    const float* hs  = (const float*)d_in[0];  // (B,T,P,C)
    const float* fm  = (const float*)d_in[2];  // (B,T)
    const float* dw  = (const float*)d_in[3];  // (R,C)
    const float* wih = (const float*)d_in[4];  // (4R,R)
    const float* whh = (const float*)d_in[5];  // (4R,R)
    const float* bih = (const float*)d_in[6];  // (4R,)
    const float* bhh = (const float*)d_in[7];  // (4R,)
    const float* up  = (const float*)d_in[8];  // (C,R)
    float* out = (float*)d_out;

    float* red = (float*)d_ws;
    float* hsm = red + (size_t)NROWS * RR;

    // K1: 512 blocks x 4 waves = 2048 waves, ~6 row-pairs each (weights amortized)
    k_down<<<512, 256, 0, stream>>>(hs, dw, fm, red);
    // K2: 197 blocks x 64 threads = exactly NSEQ*8 lanes, 1 wave/block spread wide
    k_lstm<<<197, 64, 0, stream>>>(red, fm, wih, whh, bih, bhh, hsm);
    // K3: 512 blocks x 4 waves, ~12 rows per wave
    k_up<<<512, 256, 0, stream>>>(hsm, up, out);
}